// Round 1
// baseline (186.895 us; speedup 1.0000x reference)
//
#include <hip/hip_runtime.h>

// Dims
#define B_   1024
#define S_   128
#define LP_  14
#define K_   3
#define CE_  6
#define WE_  10
#define LF_  4
#define H_   6
#define D_   14
#define T_   135
#define LW_  12
#define V_   50000
#define A_   100

// Fast overflow-safe sigmoid/tanh (inf-propagation gives correct saturation):
// x -> -inf: exp2(+inf)=inf -> rcp=0 ; x -> +inf: exp2(-inf)=0 -> 1.
static __device__ __forceinline__ float fsigm(float x) {
    return __frcp_rn(1.0f + __expf(-x));          // mul, v_exp, add, rcp
}
static __device__ __forceinline__ float ftanh(float x) {
    return fmaf(2.0f, __frcp_rn(1.0f + __expf(-2.0f * x)), -1.0f);  // mul, v_exp, add, rcp, fma
}

// ---------------- Kernel 1: char CNN + embeddings + gate-preactivation GEMV + BiLSTM ----
// One block = 4 sentences, 256 threads = 4 waves, grid 256 = 1 block/CU.
// Phase E (parallel): per word compute x[14] and BOTH directions' 24 gate pre-activations
//   (Wih·x + b) -> s_g. Moves all input-projection work off the serial recurrence.
// Phase L (serial): wave = sentence; lanes 0-5 fwd unit u, lanes 32-37 bwd unit u.
//   Each lane owns all 4 gates of its unit -> c-update lane-local, NO ds_bpermute.
//   h broadcast via v_readlane (SGPR) + cndmask. Only DS on the path: 4 prefetched
//   gate loads/step (one step ahead) + 1 h store.
__global__ __launch_bounds__(256) void k_el(
    const int* __restrict__ word_idx, const int* __restrict__ char_idx,
    const float* __restrict__ word_emb, const float* __restrict__ char_emb,
    const float* __restrict__ Wc, const float* __restrict__ bc,
    const float* __restrict__ Wih_f, const float* __restrict__ Whh_f, const float* __restrict__ b_f,
    const float* __restrict__ Wih_b, const float* __restrict__ Whh_b, const float* __restrict__ b_b,
    float* __restrict__ hbuf)
{
    __shared__ float s_g[4][S_][49];        // gate preacts: fwd rows 0-23, bwd 24-47; pad 49 (odd stride, conflict-free). 100,352 B
    __shared__ float s_h[4][S_][12];        // 24,576 B
    __shared__ float s_ce[A_ * CE_];        // 2,400 B
    __shared__ float s_wc[LF_ * K_ * CE_];  // 288 B
    __shared__ float s_bc[LF_];             // total ~127.6 KB (gfx950 WG LDS <= 160 KB)

    int t = threadIdx.x;
    for (int e = t; e < A_ * CE_; e += 256) s_ce[e] = char_emb[e];
    if (t < LF_ * K_ * CE_) s_wc[t] = Wc[t];
    if (t < LF_) s_bc[t] = bc[t];
    __syncthreads();

    // ---- Phase E: 512 words/block, 2 per thread ----
    int Wbase = blockIdx.x * 512;
    #pragma unroll
    for (int rep = 0; rep < 2; ++rep) {
        int wl = t + rep * 256;             // word-in-block
        int sent = wl >> 7;
        int step = wl & (S_ - 1);
        int w  = Wbase + wl;

        const int2* ci2 = (const int2*)(char_idx + (size_t)w * LP_);   // w*56B, 8B-aligned
        int idxs[LP_];
        #pragma unroll
        for (int p = 0; p < 7; ++p) {
            int2 v = ci2[p];
            idxs[2 * p] = v.x; idxs[2 * p + 1] = v.y;
        }
        float ce[LP_][CE_];
        #pragma unroll
        for (int p = 0; p < LP_; ++p) {
            int idx = idxs[p];
            idx = idx < 0 ? 0 : (idx >= A_ ? A_ - 1 : idx);
            #pragma unroll
            for (int c = 0; c < CE_; ++c) ce[p][c] = s_ce[idx * CE_ + c];
        }
        float x[D_];
        #pragma unroll
        for (int l = 0; l < LF_; ++l) {
            float acc[LW_];
            float bl = s_bc[l];
            #pragma unroll
            for (int q = 0; q < LW_; ++q) acc[q] = bl;
            #pragma unroll
            for (int kk = 0; kk < K_; ++kk) {
                #pragma unroll
                for (int c = 0; c < CE_; ++c) {
                    float wv_ = s_wc[l * (K_ * CE_) + kk * CE_ + c];
                    #pragma unroll
                    for (int q = 0; q < LW_; ++q) acc[q] = fmaf(ce[q + kk][c], wv_, acc[q]);
                }
            }
            float m = acc[0];
            #pragma unroll
            for (int q = 1; q < LW_; ++q) m = fmaxf(m, acc[q]);
            x[WE_ + l] = m;
        }
        int wi = word_idx[w];
        wi = wi < 0 ? 0 : (wi >= V_ ? V_ - 1 : wi);
        const float2* wep = (const float2*)(word_emb + (size_t)wi * WE_);  // wi*40B, 8B-aligned
        #pragma unroll
        for (int c = 0; c < WE_ / 2; ++c) {
            float2 v = wep[c];
            x[2 * c] = v.x; x[2 * c + 1] = v.y;
        }

        // Input projections (weights wave-uniform -> s_load/SGPR operands)
        #pragma unroll
        for (int r = 0; r < 4 * H_; ++r) {
            float a = b_f[r];
            #pragma unroll
            for (int k = 0; k < D_; ++k) a = fmaf(Wih_f[r * D_ + k], x[k], a);
            s_g[sent][step][r] = a;
        }
        #pragma unroll
        for (int r = 0; r < 4 * H_; ++r) {
            float a = b_b[r];
            #pragma unroll
            for (int k = 0; k < D_; ++k) a = fmaf(Wih_b[r * D_ + k], x[k], a);
            s_g[sent][step][24 + r] = a;
        }
    }
    __syncthreads();

    // ---- Phase L: wave = sentence; lanes 0-5 fwd, 32-37 bwd; lane u = LSTM unit u ----
    {
        int wv2  = t >> 6;
        int lane = t & 63;
        int dir  = lane >> 5;
        int l    = lane & 31;
        bool act = (l < H_);
        int u    = act ? l : (H_ - 1);

        const float* Whh = dir ? Whh_b : Whh_f;
        float whh[4][H_];                     // rows {u, 6+u, 12+u, 18+u}
        #pragma unroll
        for (int j = 0; j < 4; ++j)
            #pragma unroll
            for (int k = 0; k < H_; ++k)
                whh[j][k] = Whh[(j * H_ + u) * H_ + k];

        const float* gp = &s_g[wv2][dir ? (S_ - 1) : 0][dir * 24 + u];
        int gstride = dir ? -49 : 49;

        float hv[H_];
        #pragma unroll
        for (int k = 0; k < H_; ++k) hv[k] = 0.f;
        float c = 0.f;

        float g0 = gp[0], g1 = gp[6], g2 = gp[12], g3 = gp[18];
        for (int s = 0; s < S_; ++s) {
            float ai = g0, af = g1, ag = g2, ao = g3;
            if (s + 1 < S_) {                 // prefetch next step's preacts (off critical path)
                gp += gstride;
                g0 = gp[0]; g1 = gp[6]; g2 = gp[12]; g3 = gp[18];
            }
            #pragma unroll
            for (int k = 0; k < H_; ++k) {
                ai = fmaf(whh[0][k], hv[k], ai);
                af = fmaf(whh[1][k], hv[k], af);
                ag = fmaf(whh[2][k], hv[k], ag);
                ao = fmaf(whh[3][k], hv[k], ao);
            }
            float si = fsigm(ai);
            float sf = fsigm(af);
            float so = fsigm(ao);
            float tg = ftanh(ag);
            c = fmaf(sf, c, si * tg);
            float hu = so * ftanh(c);

            int se = dir ? (S_ - 1 - s) : s;
            if (act) s_h[wv2][se][dir * H_ + u] = hu;

            // h broadcast: readlane -> SGPR, per-half select via cndmask. No DS ops.
            #pragma unroll
            for (int k = 0; k < H_; ++k) {
                int vf = __builtin_amdgcn_readlane(__float_as_int(hu), k);
                int vb = __builtin_amdgcn_readlane(__float_as_int(hu), 32 + k);
                hv[k] = __int_as_float(dir ? vb : vf);
            }
        }
    }
    __syncthreads();

    // ---- epilogue: s_h -> hbuf coalesced: 4*128*12 = 1536 float4 ----
    {
        float4* dst = (float4*)(hbuf + (size_t)blockIdx.x * 4 * S_ * 12);
        const float4* src = (const float4*)&s_h[0][0][0];
        #pragma unroll
        for (int i = 0; i < 6; ++i) dst[t + 256 * i] = src[t + 256 * i];
    }
}

// ---------------- Kernel 2: projection + log_softmax -> out f32 [B*S][135] ----------------
// (unchanged this round — isolating the k_el delta; its true duration will surface in the
//  next round's top-5 now that k_el should drop well below it)
__global__ __launch_bounds__(256) void k_p(
    const float* __restrict__ hbuf,
    const float* __restrict__ Wt, const float* __restrict__ bt,
    float* __restrict__ out)
{
    __shared__ float s_hb[64 * 12];         // 3 KB
    int t = threadIdx.x;
    int ib = blockIdx.x * 64;               // first item of block
    {
        const float4* src = (const float4*)(hbuf + (size_t)ib * 12);
        float4* dst = (float4*)s_hb;
        if (t < 192) dst[t] = src[t];       // 64*12 floats = 192 float4, coalesced
    }
    __syncthreads();

    int lane = t & 63, wv = t >> 6;
    bool has2 = (lane < T_ - 128);
    int t2c = has2 ? (lane + 128) : (T_ - 1);

    float wA[12], wB[12], wC[12];
    #pragma unroll
    for (int jj = 0; jj < 12; ++jj) {
        wA[jj] = Wt[lane * 12 + jj];
        wB[jj] = Wt[(lane + 64) * 12 + jj];
        wC[jj] = Wt[t2c * 12 + jj];
    }
    float bA = bt[lane], bB = bt[lane + 64], bC = bt[t2c];

    int it0 = wv * 16;
    #pragma unroll 4
    for (int k = 0; k < 16; ++k) {
        int it = it0 + k;
        const float4* h4 = (const float4*)(s_hb + it * 12);   // broadcast LDS reads
        float4 a0 = h4[0], a1 = h4[1], a2 = h4[2];
        float hv[12] = {a0.x, a0.y, a0.z, a0.w, a1.x, a1.y, a1.z, a1.w, a2.x, a2.y, a2.z, a2.w};
        float y0 = bA, y1 = bB, y2 = bC;
        #pragma unroll
        for (int jj = 0; jj < 12; ++jj) {
            y0 = fmaf(hv[jj], wA[jj], y0);
            y1 = fmaf(hv[jj], wB[jj], y1);
            y2 = fmaf(hv[jj], wC[jj], y2);
        }
        // |y| small (h in (-1,1), weights ~0.1) -> exp safe without max-subtraction (validated R5)
        float ss = __expf(y0) + __expf(y1) + (has2 ? __expf(y2) : 0.0f);
        #pragma unroll
        for (int mk = 1; mk < 64; mk <<= 1) ss += __shfl_xor(ss, mk, 64);
        float ls = __logf(ss);
        float* op = out + (size_t)(ib + it) * T_;
        op[lane]      = y0 - ls;
        op[lane + 64] = y1 - ls;
        if (has2) op[lane + 128] = y2 - ls;
    }
}

extern "C" void kernel_launch(void* const* d_in, const int* in_sizes, int n_in,
                              void* d_out, int out_size, void* d_ws, size_t ws_size,
                              hipStream_t stream)
{
    const int* word_idx = (const int*)d_in[0];
    const int* char_idx = (const int*)d_in[1];
    const float* word_emb = (const float*)d_in[2];
    const float* char_emb = (const float*)d_in[3];
    const float* Wc    = (const float*)d_in[4];
    const float* bc    = (const float*)d_in[5];
    const float* Wih_f = (const float*)d_in[6];
    const float* Whh_f = (const float*)d_in[7];
    const float* b_f   = (const float*)d_in[8];
    const float* Wih_b = (const float*)d_in[9];
    const float* Whh_b = (const float*)d_in[10];
    const float* b_b   = (const float*)d_in[11];
    const float* Wt    = (const float*)d_in[12];
    const float* bt    = (const float*)d_in[13];

    float* hbuf = (float*)d_ws;    // B*S*12 f32 = 6.3 MB

    k_el<<<B_ / 4, 256, 0, stream>>>(word_idx, char_idx, word_emb, char_emb, Wc, bc,
                                     Wih_f, Whh_f, b_f, Wih_b, Whh_b, b_b, hbuf);
    k_p<<<(B_ * S_) / 64, 256, 0, stream>>>(hbuf, Wt, bt, (float*)d_out);
}